// Round 7
// baseline (1087.690 us; speedup 1.0000x reference)
//
#include <hip/hip_runtime.h>
#include <math.h>

#pragma clang fp contract(off)

#define BB 32
#define CC 64
#define LL 8192
#define NW 1021      // number of spectral windows: (8192-32)/8 + 1
#define MAXSEG 1024
#define MAXTOK 1024
#define BNDCAP 1026
#define NBINS (LL / 2)   // 4096 flat bins per batch (segments partition [0,L))

// DP blocking parameters
#define DP_T 64          // ends per block
#define DP_NBLK 16       // ceil(NW / DP_T)
#define DP_MARGIN 1e-6   // screen margin; approx-vs-exact error <= ~1e-11

// ---------------------------------------------------------------------------
// numpy pairwise_sum replica (loops.c.src): n<8 sequential, n<=128 blocked with
// 8 accumulators, else recursive halving with n2 -= n2 % 8.
// ---------------------------------------------------------------------------
template <typename F>
__device__ double np_pairwise(const F& f, int off, int n) {
  if (n < 8) {
    double res = 0.0;
    for (int i = 0; i < n; i++) res = res + f(off + i);
    return res;
  }
  if (n <= 128) {
    double r0 = f(off + 0), r1 = f(off + 1), r2 = f(off + 2), r3 = f(off + 3);
    double r4 = f(off + 4), r5 = f(off + 5), r6 = f(off + 6), r7 = f(off + 7);
    int i = 8;
    int lim = n - (n % 8);
    for (; i < lim; i += 8) {
      r0 = r0 + f(off + i + 0); r1 = r1 + f(off + i + 1);
      r2 = r2 + f(off + i + 2); r3 = r3 + f(off + i + 3);
      r4 = r4 + f(off + i + 4); r5 = r5 + f(off + i + 5);
      r6 = r6 + f(off + i + 6); r7 = r7 + f(off + i + 7);
    }
    double res = ((r0 + r1) + (r2 + r3)) + ((r4 + r5) + (r6 + r7));
    for (; i < n; i++) res = res + f(off + i);
    return res;
  }
  int n2 = n / 2;
  n2 -= n2 % 8;
  return np_pairwise(f, off, n2) + np_pairwise(f, off + n2, n - n2);
}

// ---------------------------------------------------------------------------
// Wave-parallel exact replica of numpy pairwise_sum (see r4 notes).
// ---------------------------------------------------------------------------
template <int KIND>
__device__ __noinline__ double wp_leaf(const double* __restrict__ pp, double cent,
                                       int off, int n, int lane) {
  int k = lane & 7;
  auto f = [&](int i) -> double {
    double pv = pp[i];
    if constexpr (KIND == 0) {
      return pv;
    } else if constexpr (KIND == 1) {
      return pv * (double)(i + 1);
    } else {
      double d = (double)(i + 1) - cent;
      double dd = d * d;
      return dd * pv;
    }
  };
  double r = f(off + k);
  int lim = n - (n % 8);
  for (int i = 8; i < lim; i += 8) r = r + f(off + i + k);
  double a = r + __shfl_xor(r, 1, 64);
  double b2 = a + __shfl_xor(a, 2, 64);
  double res = b2 + __shfl_xor(b2, 4, 64);
  for (int i = lim; i < n; i++) res = res + f(off + i);
  return res;
}

template <int DEPTH, int KIND>
__device__ double wp_tree(const double* __restrict__ pp, double cent, int off,
                          int n, int lane) {
  if (n <= 128) return wp_leaf<KIND>(pp, cent, off, n, lane);
  if constexpr (DEPTH > 0) {
    int n2 = n / 2;
    n2 -= n2 % 8;
    double l = wp_tree<DEPTH - 1, KIND>(pp, cent, off, n2, lane);
    double r = wp_tree<DEPTH - 1, KIND>(pp, cent, off + n2, n - n2, lane);
    return l + r;
  } else {
    if constexpr (KIND == 0)
      return np_pairwise([&](int i) { return pp[i]; }, off, n);
    else if constexpr (KIND == 1)
      return np_pairwise([&](int i) { return pp[i] * (double)(i + 1); }, off, n);
    else
      return np_pairwise(
          [&](int i) {
            double d = (double)(i + 1) - cent;
            double dd = d * d;
            return dd * pp[i];
          },
          off, n);
  }
}

// ---------------------------------------------------------------------------
// Stage 1: agg[b][l] = channel mean, numpy sequential f32 order.
// ---------------------------------------------------------------------------
__global__ void k_agg(const float* __restrict__ x, double* __restrict__ agg) {
  int idx = blockIdx.x * blockDim.x + threadIdx.x;
  if (idx >= BB * LL) return;
  int b = idx / LL, l = idx - b * LL;
  const float* xb = x + (size_t)b * CC * LL + l;
  float s = 0.0f;
  for (int c = 0; c < CC; c++) s = s + xb[(size_t)c * LL];
  agg[idx] = (double)(s / 64.0f);
}

// ---------------------------------------------------------------------------
// Stage 2: per-window spectral features (32-pt DFT, bins 1..16).
// ---------------------------------------------------------------------------
__global__ void k_winfeat(const double* __restrict__ agg, double* __restrict__ feat) {
  __shared__ double tc[32], tsn[32];
  if (threadIdx.x < 32) {
    double th = 6.283185307179586 * ((double)threadIdx.x / 32.0);
    tc[threadIdx.x] = cos(th);
    tsn[threadIdx.x] = sin(th);
  }
  __syncthreads();
  int idx = blockIdx.x * blockDim.x + threadIdx.x;
  if (idx >= BB * NW) return;
  int b = idx / NW, w = idx - b * NW;
  const double* a = agg + (size_t)b * LL + (size_t)w * 8;
  double av[32];
#pragma unroll
  for (int t = 0; t < 32; t++) av[t] = a[t];
  double p[16];
  for (int k = 1; k <= 16; k++) {
    double re = 0.0, im = 0.0;
    int m = 0;
    for (int t = 0; t < 32; t++) {
      re = re + av[t] * tc[m];
      im = im + av[t] * tsn[m];
      m = (m + k) & 31;
    }
    p[k - 1] = re * re + im * im;
  }
  double r[8];
  for (int i = 0; i < 8; i++) r[i] = p[i] + p[i + 8];
  double sum = ((r[0] + r[1]) + (r[2] + r[3])) + ((r[4] + r[5]) + (r[6] + r[7]));
  double tot = (sum > 1e-8) ? sum : 1e-8;
  double pf[16];
  for (int i = 0; i < 16; i++) pf[i] = p[i] * (double)(i + 1);
  for (int i = 0; i < 8; i++) r[i] = pf[i] + pf[i + 8];
  double spf = ((r[0] + r[1]) + (r[2] + r[3])) + ((r[4] + r[5]) + (r[6] + r[7]));
  int dom = 0;
  double bv = p[0];
  for (int i = 1; i < 16; i++)
    if (p[i] > bv) { bv = p[i]; dom = i; }
  dom += 1;
  double cent = spf / tot;
  double q[16];
  for (int i = 0; i < 16; i++) {
    double d = (double)(i + 1) - cent;
    double dd = d * d;
    q[i] = dd * p[i];
  }
  for (int i = 0; i < 8; i++) r[i] = q[i] + q[i + 8];
  double sv = ((r[0] + r[1]) + (r[2] + r[3])) + ((r[4] + r[5]) + (r[6] + r[7]));
  double var = sv / tot;
  double bw = sqrt(var > 0.0 ? var : 0.0) / 32.0;
  double mean = sum / 16.0;
  double* f = feat + ((size_t)b * NW + (size_t)w) * 3;
  f[0] = (double)dom / 32.0;
  f[1] = bw;
  f[2] = log1p(mean);
}

// ---------------------------------------------------------------------------
// Stage 3: PELT DP — overlapped schedule (see r5 notes). Unchanged.
// ---------------------------------------------------------------------------
__global__ __launch_bounds__(1024) void k_dp(const double* __restrict__ feat,
                                             int* __restrict__ bnd_g,
                                             int* __restrict__ nbnd_g,
                                             int* __restrict__ seg_s,
                                             int* __restrict__ seg_e,
                                             int* __restrict__ nseg_g) {
  __shared__ double cmb[NW + 1][8];        // 65,408 B
  __shared__ double sseT[2][DP_T][DP_T];   // 65,536 B (buf0 doubles as staging)
  __shared__ double pvL[24][DP_T];         // 12,288 B  [class][lane]
  __shared__ int pixL[24][DP_T];           //  6,144 B
  __shared__ int prevL[NW + 1];            //  4,088 B
  __shared__ double invL[NW + 1];          //  8,176 B   total 161,640 B
  int b = blockIdx.x;
  int tid = threadIdx.x;
  const double* fb = feat + (size_t)b * NW * 3;

  double* featS = &sseT[0][0][0];  // 4096 doubles >= NW*3 = 3063
  for (int i = tid; i < NW * 3; i += 1024) featS[i] = fb[i];
  for (int i = tid + 1; i <= NW; i += 1024) invL[i] = 1.0 / (double)i;
  for (int i = tid; i < 24 * DP_T; i += 1024) {
    (&pvL[0][0])[i] = __builtin_inf();
    (&pixL[0][0])[i] = 0;
  }
  if (tid == 0) {
    cmb[0][0] = 0.0; cmb[0][1] = 0.0; cmb[0][2] = 0.0;
    cmb[0][3] = 0.0;   // w0 = dp0 + 1 - qs0 = 0
    cmb[0][4] = -1.0;  // dp[0] = -penalty
    cmb[0][5] = 0.0; cmb[0][6] = 0.0; cmb[0][7] = 0.0;
  }
  __syncthreads();

  // 6 sequential prefix chains (3 ch x {sum,sumsq}); np.cumsum order exact.
  if (tid < 6) {
    int c = tid % 3;
    bool sq = tid >= 3;
    int col = sq ? 5 + c : c;
    double acc = 0.0;
    for (int i = 0; i < NW; i++) {
      double f = featS[i * 3 + c];
      double v = sq ? f * f : f;
      acc = acc + v;
      cmb[i + 1][col] = acc;
    }
  }
  __syncthreads();

  int lane = tid & 63;
  int w = tid >> 6;

  // Prologue: triangle for block 0 (featS fully consumed above).
  {
    int end = 1 + lane;
    double pe0 = cmb[end][0], pe1 = cmb[end][1], pe2 = cmb[end][2];
    double qe0 = cmb[end][5], qe1 = cmb[end][6], qe2 = cmb[end][7];
    for (int s = w; s < DP_T; s += 16) {
      double sl = (double)(end - s);
      double s0 = pe0 - cmb[s][0], s1 = pe1 - cmb[s][1], s2 = pe2 - cmb[s][2];
      double u0 = s0 * s0, u1 = s1 * s1, u2 = s2 * s2;
      double t0 = (qe0 - cmb[s][5]) - u0 / sl;
      double t1 = (qe1 - cmb[s][6]) - u1 / sl;
      double t2 = (qe2 - cmb[s][7]) - u2 / sl;
      sseT[0][s][lane] = (t0 + t1) + t2;
    }
  }
  __syncthreads();

  double dpLast = -1.0;

  for (int blk = 0; blk < DP_NBLK; blk++) {
    int cur = blk & 1, nxt = cur ^ 1;
    int e0 = blk * DP_T;
    int ecnt = NW - e0;
    if (ecnt > DP_T) ecnt = DP_T;
    bool hasNext = (blk + 1 < DP_NBLK);
    double vBig = __builtin_inf();
    int ixBig = 0;

    // ---- SEG A ----
    if (w == 0) {
      int end = e0 + 1 + lane;
      if (end > NW) end = NW;
      double vcur = pvL[0][lane];
      int ixcur = pixL[0][lane];
#pragma unroll
      for (int t = 1; t < 23; t++) {
        double ov = pvL[t][lane];
        int oi = pixL[t][lane];
        if (ov < vcur || (ov == vcur && oi < ixcur)) { vcur = ov; ixcur = oi; }
      }
      double qsE = (cmb[end][5] + cmb[end][6]) + cmb[end][7];
      // Phase B serial chain over the precomputed triangle.
      double sse_next = sseT[cur][0][lane];
      for (int s = 0; s < ecnt; s++) {
        double sse_cur = sse_next;
        if (s + 1 < ecnt) sse_next = sseT[cur][s + 1][lane];
        double dpj = (s == 0) ? dpLast : __shfl(vcur, s - 1, 64);
        double cand = (dpj + sse_cur) + 1.0;
        if (lane >= s && cand < vcur) { vcur = cand; ixcur = e0 + s; }
        if (lane == s) {
          cmb[end][4] = vcur;
          prevL[end] = ixcur;
          cmb[end][3] = (vcur + 1.0) - qsE;  // screen fold w
        }
      }
      dpLast = __shfl(vcur, ecnt - 1, 64);
    } else if (hasNext) {
      int e0n = e0 + DP_T;
      int ecn = NW - e0n;
      if (ecn > DP_T) ecn = DP_T;
      int endn = e0n + 1 + lane;
      if (endn > NW) endn = NW;
      double pn0 = cmb[endn][0], pn1 = cmb[endn][1], pn2 = cmb[endn][2];
      double qn0 = cmb[endn][5], qn1 = cmb[endn][6], qn2 = cmb[endn][7];
      // Triangle for block blk+1.
      for (int s = w - 1; s < ecn; s += 15) {
        int j = e0n + s;
        double sl = (double)(endn - j);
        double s0 = pn0 - cmb[j][0], s1 = pn1 - cmb[j][1], s2 = pn2 - cmb[j][2];
        double u0 = s0 * s0, u1 = s1 * s1, u2 = s2 * s2;
        double t0 = (qn0 - cmb[j][5]) - u0 / sl;
        double t1 = (qn1 - cmb[j][6]) - u1 / sl;
        double t2 = (qn2 - cmb[j][7]) - u2 / sl;
        sseT[nxt][s][lane] = (t0 + t1) + t2;
      }
      // Big scan for E_{blk+1} over j < e0, class (w-1) mod 15, top-2 screen.
      double qeS = (qn0 + qn1) + qn2;
      double m1 = __builtin_inf(), m2 = __builtin_inf();
      int ix1 = -1;
      for (int j = w - 1; j < e0; j += 15) {
        double p0 = cmb[j][0], p1 = cmb[j][1], p2 = cmb[j][2], wj = cmb[j][3];
        double inv = invL[endn - j];
        double s0 = pn0 - p0, s1 = pn1 - p1, s2 = pn2 - p2;
        double us = fma(s2, s2, fma(s1, s1, s0 * s0));
        double candA = fma(-us, inv, wj + qeS);
        if (candA < m1) { m2 = m1; m1 = candA; ix1 = j; }
        else if (candA < m2) { m2 = candA; }
      }
      if (ix1 >= 0) {
        if (m2 - m1 > DP_MARGIN) {
          int j = ix1;
          double p0 = cmb[j][0], p1 = cmb[j][1], p2 = cmb[j][2];
          double q0 = cmb[j][5], q1 = cmb[j][6], q2 = cmb[j][7];
          double dpj = cmb[j][4];
          double sl = (double)(endn - j);
          double s0 = pn0 - p0, s1 = pn1 - p1, s2 = pn2 - p2;
          double u0 = s0 * s0, u1 = s1 * s1, u2 = s2 * s2;
          double t0 = (qn0 - q0) - u0 / sl;
          double t1 = (qn1 - q1) - u1 / sl;
          double t2 = (qn2 - q2) - u2 / sl;
          vBig = (dpj + ((t0 + t1) + t2)) + 1.0;
          ixBig = j;
        } else {
          double thr = m1 + DP_MARGIN;
          for (int j = w - 1; j < e0; j += 15) {
            double p0 = cmb[j][0], p1 = cmb[j][1], p2 = cmb[j][2], wj = cmb[j][3];
            double inv = invL[endn - j];
            double s0 = pn0 - p0, s1 = pn1 - p1, s2 = pn2 - p2;
            double us = fma(s2, s2, fma(s1, s1, s0 * s0));
            double candA = fma(-us, inv, wj + qeS);
            if (candA <= thr) {
              double q0 = cmb[j][5], q1 = cmb[j][6], q2 = cmb[j][7];
              double dpj = cmb[j][4];
              double sl = (double)(endn - j);
              double u0 = s0 * s0, u1 = s1 * s1, u2 = s2 * s2;
              double t0 = (qn0 - q0) - u0 / sl;
              double t1 = (qn1 - q1) - u1 / sl;
              double t2 = (qn2 - q2) - u2 / sl;
              double cand = (dpj + ((t0 + t1) + t2)) + 1.0;
              if (cand < vBig || (cand == vBig && j < ixBig)) { vBig = cand; ixBig = j; }
            }
          }
        }
      }
    }
    __syncthreads();
    // ---- SEG B ----
    if (hasNext) {
      if (w >= 1) {
        pvL[w - 1][lane] = vBig;
        pixL[w - 1][lane] = ixBig;
      }
      if (w < 8) {
        int e0n = e0 + DP_T;
        int endn = e0n + 1 + lane;
        if (endn > NW) endn = NW;
        double pn0 = cmb[endn][0], pn1 = cmb[endn][1], pn2 = cmb[endn][2];
        double qn0 = cmb[endn][5], qn1 = cmb[endn][6], qn2 = cmb[endn][7];
        double qeS = (qn0 + qn1) + qn2;
        double m1 = __builtin_inf(), m2 = __builtin_inf();
        int ix1 = 0;
        int j0 = e0 + w * 8;
        for (int i = 0; i < 8; i++) {
          int j = j0 + i;
          double p0 = cmb[j][0], p1 = cmb[j][1], p2 = cmb[j][2], wj = cmb[j][3];
          double inv = invL[endn - j];
          double s0 = pn0 - p0, s1 = pn1 - p1, s2 = pn2 - p2;
          double us = fma(s2, s2, fma(s1, s1, s0 * s0));
          double candA = fma(-us, inv, wj + qeS);
          if (candA < m1) { m2 = m1; m1 = candA; ix1 = j; }
          else if (candA < m2) { m2 = candA; }
        }
        double v = __builtin_inf();
        int ix = 0;
        if (m2 - m1 > DP_MARGIN) {
          int j = ix1;
          double p0 = cmb[j][0], p1 = cmb[j][1], p2 = cmb[j][2];
          double q0 = cmb[j][5], q1 = cmb[j][6], q2 = cmb[j][7];
          double dpj = cmb[j][4];
          double sl = (double)(endn - j);
          double s0 = pn0 - p0, s1 = pn1 - p1, s2 = pn2 - p2;
          double u0 = s0 * s0, u1 = s1 * s1, u2 = s2 * s2;
          double t0 = (qn0 - q0) - u0 / sl;
          double t1 = (qn1 - q1) - u1 / sl;
          double t2 = (qn2 - q2) - u2 / sl;
          v = (dpj + ((t0 + t1) + t2)) + 1.0;
          ix = j;
        } else {
          double thr = m1 + DP_MARGIN;
          for (int i = 0; i < 8; i++) {
            int j = j0 + i;
            double p0 = cmb[j][0], p1 = cmb[j][1], p2 = cmb[j][2], wj = cmb[j][3];
            double inv = invL[endn - j];
            double s0 = pn0 - p0, s1 = pn1 - p1, s2 = pn2 - p2;
            double us = fma(s2, s2, fma(s1, s1, s0 * s0));
            double candA = fma(-us, inv, wj + qeS);
            if (candA <= thr) {
              double q0 = cmb[j][5], q1 = cmb[j][6], q2 = cmb[j][7];
              double dpj = cmb[j][4];
              double sl = (double)(endn - j);
              double u0 = s0 * s0, u1 = s1 * s1, u2 = s2 * s2;
              double t0 = (qn0 - q0) - u0 / sl;
              double t1 = (qn1 - q1) - u1 / sl;
              double t2 = (qn2 - q2) - u2 / sl;
              double cand = (dpj + ((t0 + t1) + t2)) + 1.0;
              if (cand < v || (cand == v && j < ix)) { v = cand; ix = j; }
            }
          }
        }
        pvL[15 + w][lane] = v;
        pixL[15 + w][lane] = ix;
      }
    }
    __syncthreads();
  }

  if (tid == 0) {
    int* chain = (int*)cmb;   // reuse LDS
    int cnt = 0, i = NW;
    while (i > 0) { i = prevL[i]; chain[cnt++] = i; }
    int* bbL = (int*)invL;    // reuse LDS (1026 ints fit in 8176 B)
    int nb = 0;
    bbL[nb++] = 0;
    for (int t = cnt - 2; t >= 0; t--) {  // interior breakpoints, ascending
      int w2 = chain[t];
      int tt = w2 * 8;
      if (tt <= bbL[nb - 1]) continue;
      if (tt - bbL[nb - 1] < 8) continue;
      if (LL - tt < 8) continue;
      bbL[nb++] = tt;
    }
    bbL[nb++] = LL;
    int* bb = bnd_g + (size_t)b * BNDCAP;
    for (int t = 0; t < nb; t++) bb[t] = bbL[t];
    nbnd_g[b] = nb;
    int nseg = nb - 1;
    nseg_g[b] = nseg;
    for (int si = 0; si < nseg; si++) {
      seg_s[(size_t)b * MAXSEG + si] = bbL[si];
      seg_e[(size_t)b * MAXSEG + si] = bbL[si + 1];
    }
  }
}

// ---------------------------------------------------------------------------
// Stage 4: all DFT bins, Goertzel + 8-way split.
// Segment [s,e), n = e-s (multiple of 8), owns flat bins [s/2, e/2),
// k = g - s/2 + 1. Thread (g, h in {0..7}) runs Goertzel over eighth h
// (m = n/8 elems): S_h = Sum_j a_{hm+j} e^{+i th j}. Combine:
// X = Sum_h e^{+i pi k h / 4} S_h (exact period-8 phase; rotation iterated
// in-register, err ~1e-15 << the accepted ~1e-10 Goertzel deviation).
// 8-way split: chain latency n/8 (4x less than r5's n/2) and grid 64x32 =
// 2048 blocks -> no longer grid-capped at 50% occupancy (r5: 512 blocks).
// ---------------------------------------------------------------------------
__global__ __launch_bounds__(512) void k_bins(const double* __restrict__ agg,
                                              const int* __restrict__ bnd_g,
                                              const int* __restrict__ nbnd_g,
                                              double* __restrict__ segp) {
#pragma clang fp contract(fast)
  __shared__ int bbS[BNDCAP];
  __shared__ double reS[512], imS[512];
  int b = blockIdx.y;
  int nb = nbnd_g[b];
  for (int i = threadIdx.x; i < nb; i += 512) bbS[i] = bnd_g[(size_t)b * BNDCAP + i];
  __syncthreads();
  int gl = threadIdx.x & 63;
  int h = threadIdx.x >> 6;      // eighth index 0..7
  int g = blockIdx.x * 64 + gl;  // flat bin 0..4095
  int pos = g * 2;
  int lo = 0, hi = nb - 1;
  while (hi - lo > 1) {
    int mid = (lo + hi) >> 1;
    if (bbS[mid] <= pos) lo = mid; else hi = mid;
  }
  int s = bbS[lo], e = bbS[lo + 1];
  int n = e - s;
  int k = g - s / 2 + 1;  // 1..n/2
  int m = n >> 3;         // per-eighth length >= 1 (n multiple of 8)
  const double* ab = agg + (size_t)b * LL + s + h * m;
  double th = 6.283185307179586 * ((double)k / (double)n);
  double cth = cos(th), sth = sin(th);
  double c2 = 2.0 * cth;
  double s1 = 0.0, s2 = 0.0;
  for (int t = m - 1; t >= 0; t--) {
    double x = (ab[t] - s2) + c2 * s1;
    s2 = s1;
    s1 = x;
  }
  // S_h = (s_0 - cos*s_1) + i sin*s_1
  double re = s1 - cth * s2;
  double im = sth * s2;
  reS[threadIdx.x] = re;
  imS[threadIdx.x] = im;
  __syncthreads();
  if (h == 0) {
    // w = e^{+i pi (k&7) / 4}; advance w^h by in-register complex rotation.
    double th2 = 0.7853981633974483 * (double)(k & 7);
    double wc = cos(th2), ws = sin(th2);
    double cc = wc, ss = ws;
    double rr = re, ii = im;
    for (int hh = 1; hh < 8; hh++) {
      double rh = reS[hh * 64 + gl], ih = imS[hh * 64 + gl];
      rr += rh * cc - ih * ss;
      ii += rh * ss + ih * cc;
      double nc = cc * wc - ss * ws;
      double ns = ss * wc + cc * ws;
      cc = nc; ss = ns;
    }
    segp[(size_t)b * NBINS + g] = rr * rr + ii * ii;
  }
}

// ---------------------------------------------------------------------------
// Stage 4c: per-segment stats, one wave per segment (exact numpy replicas).
// ---------------------------------------------------------------------------
__global__ __launch_bounds__(256) void k_segfin(
    const double* __restrict__ segp, const int* __restrict__ seg_s,
    const int* __restrict__ seg_e, const int* __restrict__ nseg_g,
    int* __restrict__ seg_pl, double* __restrict__ seg_domp,
    double* __restrict__ seg_bw) {
  __shared__ double ppS[NBINS];  // 32 KB
  int b = blockIdx.x;
  for (int i = threadIdx.x; i < NBINS; i += 256) ppS[i] = segp[(size_t)b * NBINS + i];
  __syncthreads();
  int ns = nseg_g[b];
  int lane = threadIdx.x & 63;
  int wid = threadIdx.x >> 6;
  for (int si = wid; si < ns; si += 4) {
    int s = seg_s[(size_t)b * MAXSEG + si];
    int e = seg_e[(size_t)b * MAXSEG + si];
    int n = e - s;
    int nb2 = n / 2;
    int base = s / 2;
    double domp, bwv;
    if (n < 2) {
      domp = 1.0; bwv = 0.0;
    } else if (nb2 <= 1) {
      domp = (double)n; bwv = 0.0;
    } else {
      const double* pp = ppS + base;
      double sum, spf, sv;
      if (nb2 < 8) {
        sum = 0.0;
        for (int i = 0; i < nb2; i++) sum = sum + pp[i];
      } else {
        sum = wp_tree<7, 0>(pp, 0.0, 0, nb2, lane);
      }
      double tot = (sum > 1e-8) ? sum : 1e-8;
      int ch = (nb2 + 63) >> 6;
      double bv = -1.0;
      int bi = 0x7fffffff;
      int st = lane * ch;
      int en2 = st + ch;
      if (en2 > nb2) en2 = nb2;
      if (st < nb2) {
        bv = pp[st]; bi = st;
        for (int i = st + 1; i < en2; i++) {
          double pv = pp[i];
          if (pv > bv) { bv = pv; bi = i; }
        }
      }
      for (int o = 32; o; o >>= 1) {
        double ov = __shfl_xor(bv, o, 64);
        int oi = __shfl_xor(bi, o, 64);
        if (ov > bv || (ov == bv && oi < bi)) { bv = ov; bi = oi; }
      }
      int dom = bi + 1;
      if (nb2 < 8) {
        spf = 0.0;
        for (int i = 0; i < nb2; i++) spf = spf + pp[i] * (double)(i + 1);
      } else {
        spf = wp_tree<7, 1>(pp, 0.0, 0, nb2, lane);
      }
      double cent = spf / tot;
      if (nb2 < 8) {
        sv = 0.0;
        for (int i = 0; i < nb2; i++) {
          double d = (double)(i + 1) - cent;
          double dd = d * d;
          sv = sv + dd * pp[i];
        }
      } else {
        sv = wp_tree<7, 2>(pp, cent, 0, nb2, lane);
      }
      double var = sv / tot;
      bwv = sqrt(var > 0.0 ? var : 0.0) / (double)n;
      domp = (double)n / (double)dom;
    }
    double raw = (1.0 * domp) / (1.0 + 1.0 * bwv);
    int pl = (int)rint(raw / 2.0) * 2;  // Python round = half-to-even
    if (pl < 8) pl = 8;
    if (pl > 64) pl = 64;
    if (lane == 0) {
      seg_pl[(size_t)b * MAXSEG + si] = pl;
      seg_domp[(size_t)b * MAXSEG + si] = domp;
      seg_bw[(size_t)b * MAXSEG + si] = bwv;
    }
  }
}

// ---------------------------------------------------------------------------
// Stage 5: token enumeration (one thread per batch) + n_tokens output.
// ---------------------------------------------------------------------------
__global__ void k_tokens(const int* __restrict__ seg_s, const int* __restrict__ seg_e,
                         const int* __restrict__ seg_pl, const int* __restrict__ nseg_g,
                         int* __restrict__ tok_a, int* __restrict__ tok_z,
                         int* __restrict__ tok_sg, int* __restrict__ ntok_g,
                         float* __restrict__ out_nt) {
  int b = blockIdx.x * blockDim.x + threadIdx.x;
  if (b >= BB) return;
  int ns = nseg_g[b];
  int cnt = 0;
  for (int si = 0; si < ns; si++) {
    int s = seg_s[(size_t)b * MAXSEG + si];
    int e = seg_e[(size_t)b * MAXSEG + si];
    int pl = seg_pl[(size_t)b * MAXSEG + si];
    for (int a = s; a < e; a += pl) {
      int z = a + pl;
      if (z > e) z = e;
      tok_a[(size_t)b * MAXTOK + cnt] = a;
      tok_z[(size_t)b * MAXTOK + cnt] = z;
      tok_sg[(size_t)b * MAXTOK + cnt] = si;
      cnt++;
    }
  }
  ntok_g[b] = cnt;
  out_nt[b] = (float)cnt;
}

// ---------------------------------------------------------------------------
// Stage 6: per-token metadata outputs (zero-fills padding; no big memset).
// ---------------------------------------------------------------------------
__global__ void k_tokfill(const int* __restrict__ tok_a, const int* __restrict__ tok_z,
                          const int* __restrict__ tok_sg, const int* __restrict__ ntok_g,
                          const int* __restrict__ seg_s, const int* __restrict__ seg_e,
                          const double* __restrict__ seg_domp,
                          const double* __restrict__ seg_bw, float* __restrict__ out,
                          int mx) {
  int b = blockIdx.x;
  int t = blockIdx.y * blockDim.x + threadIdx.x;
  if (t >= mx) return;
  size_t BM = (size_t)BB * (size_t)mx;
  float* mask = out + BM * 1024;
  float* start = mask + BM;
  float* endo = start + BM;
  float* cen = endo + BM;
  float* span = cen + BM;
  float* reg = span + BM;
  size_t o = (size_t)b * (size_t)mx + t;
  if (t >= ntok_g[b]) {
    mask[o] = 0.0f; start[o] = 0.0f; endo[o] = 0.0f;
    cen[o] = 0.0f; span[o] = 0.0f;
    reg[o * 3 + 0] = 0.0f; reg[o * 3 + 1] = 0.0f; reg[o * 3 + 2] = 0.0f;
    return;
  }
  int a = tok_a[(size_t)b * MAXTOK + t];
  int z = tok_z[(size_t)b * MAXTOK + t];
  int si = tok_sg[(size_t)b * MAXTOK + t];
  mask[o] = 1.0f;
  start[o] = (float)a;
  endo[o] = (float)z;
  cen[o] = (float)(((double)(a + z - 1) * 0.5) / 8191.0);
  span[o] = (float)((double)(z - a) / 8192.0);
  int s = seg_s[(size_t)b * MAXSEG + si];
  int e = seg_e[(size_t)b * MAXSEG + si];
  reg[o * 3 + 0] = (float)(seg_domp[(size_t)b * MAXSEG + si] / 8192.0);
  reg[o * 3 + 1] = (float)seg_bw[(size_t)b * MAXSEG + si];
  reg[o * 3 + 2] = (float)((double)(e - s) / 8192.0);
}

// ---------------------------------------------------------------------------
// Stage 7: patch gather (zero-fills padding).
// ---------------------------------------------------------------------------
__global__ __launch_bounds__(256) void k_patches(const float* __restrict__ x,
                                                 const int* __restrict__ tok_a,
                                                 const int* __restrict__ tok_z,
                                                 const int* __restrict__ ntok_g,
                                                 float* __restrict__ out, int mx) {
  int t = blockIdx.x, b = blockIdx.y;
  float* ob = out + (((size_t)b * (size_t)mx + t) * CC) * 16;
  if (t >= ntok_g[b]) {
    for (int e2 = threadIdx.x; e2 < CC * 16; e2 += 256) ob[e2] = 0.0f;
    return;
  }
  __shared__ int g0[16], g1[16];
  __shared__ float wS[16];
  if (threadIdx.x < 16) {
    int a = tok_a[(size_t)b * MAXTOK + t];
    int z = tok_z[(size_t)b * MAXTOK + t];
    int n = z - a;
    double src = ((double)threadIdx.x + 0.5) * ((double)n / 16.0) - 0.5;
    if (src < 0.0) src = 0.0;
    double hi = (double)n - 1.0;
    if (src > hi) src = hi;
    double fi = floor(src);
    int i0 = (int)fi;
    int i1 = i0 + 1;
    if (i1 > n - 1) i1 = n - 1;
    g0[threadIdx.x] = a + i0;
    g1[threadIdx.x] = a + i1;
    wS[threadIdx.x] = (float)(src - fi);
  }
  __syncthreads();
  const float* xb = x + (size_t)b * CC * LL;
  for (int e2 = threadIdx.x; e2 < CC * 16; e2 += 256) {
    int c = e2 >> 4, ai = e2 & 15;
    float wv = wS[ai];
    float v0 = xb[(size_t)c * LL + g0[ai]];
    float v1 = xb[(size_t)c * LL + g1[ai]];
    ob[e2] = v0 * (1.0f - wv) + v1 * wv;
  }
}

extern "C" void kernel_launch(void* const* d_in, const int* in_sizes, int n_in,
                              void* d_out, int out_size, void* d_ws, size_t ws_size,
                              hipStream_t stream) {
  (void)in_sizes; (void)n_in; (void)ws_size;
  const float* x = (const float*)d_in[0];
  float* out = (float*)d_out;
  // out_size = B*(1032*mx + 1)  -> recover mx
  long mx = ((long)out_size / BB - 1) / 1032;
  if (mx < 1) mx = 1;

  char* wp = (char*)d_ws;
  size_t off = 0;
  auto carve = [&](size_t bytes) -> void* {
    void* p = wp + off;
    off += (bytes + 255) & ~(size_t)255;
    return p;
  };
  double* agg = (double*)carve((size_t)BB * LL * 8);
  double* feat = (double*)carve((size_t)BB * NW * 3 * 8);
  double* segp = (double*)carve((size_t)BB * NBINS * 8);
  double* seg_domp = (double*)carve((size_t)BB * MAXSEG * 8);
  double* seg_bw = (double*)carve((size_t)BB * MAXSEG * 8);
  int* bnd = (int*)carve((size_t)BB * BNDCAP * 4);
  int* nbnd = (int*)carve((size_t)BB * 4);
  int* seg_s = (int*)carve((size_t)BB * MAXSEG * 4);
  int* seg_e = (int*)carve((size_t)BB * MAXSEG * 4);
  int* seg_pl = (int*)carve((size_t)BB * MAXSEG * 4);
  int* nseg = (int*)carve((size_t)BB * 4);
  int* tok_a = (int*)carve((size_t)BB * MAXTOK * 4);
  int* tok_z = (int*)carve((size_t)BB * MAXTOK * 4);
  int* tok_sg = (int*)carve((size_t)BB * MAXTOK * 4);
  int* ntok = (int*)carve((size_t)BB * 4);

  k_agg<<<(BB * LL + 255) / 256, 256, 0, stream>>>(x, agg);
  k_winfeat<<<(BB * NW + 255) / 256, 256, 0, stream>>>(agg, feat);
  k_dp<<<BB, 1024, 0, stream>>>(feat, bnd, nbnd, seg_s, seg_e, nseg);
  dim3 gb(NBINS / 64, BB);
  k_bins<<<gb, 512, 0, stream>>>(agg, bnd, nbnd, segp);
  k_segfin<<<BB, 256, 0, stream>>>(segp, seg_s, seg_e, nseg, seg_pl, seg_domp,
                                   seg_bw);
  k_tokens<<<1, 64, 0, stream>>>(seg_s, seg_e, seg_pl, nseg, tok_a, tok_z,
                                 tok_sg, ntok, out + (size_t)BB * (size_t)mx * 1032);
  dim3 gf(BB, (unsigned)((mx + 255) / 256));
  k_tokfill<<<gf, 256, 0, stream>>>(tok_a, tok_z, tok_sg, ntok, seg_s, seg_e,
                                    seg_domp, seg_bw, out, (int)mx);
  dim3 gp((unsigned)mx, BB);
  k_patches<<<gp, 256, 0, stream>>>(x, tok_a, tok_z, ntok, out, (int)mx);
}